// Round 1
// baseline (915.683 us; speedup 1.0000x reference)
//
#include <hip/hip_runtime.h>

#define N_NODES   50000
#define N_EDGES   800000
#define HIDDEN    100
#define NUM_TASKS 128
#define NUM_GRAPHS 2000
#define EPS 1e-16f

static __device__ __forceinline__ float invclip(float v) {
    // clip(v, EPS, 100) ** -1
    return 1.0f / fminf(fmaxf(v, EPS), 100.0f);
}

// ---- init: deg=1 (self loop), cursor=0, pooled=0, gcnt=0 ----
__global__ void init_kernel(int* __restrict__ deg, int* __restrict__ cursor,
                            float* __restrict__ pooled, float* __restrict__ gcnt) {
    int i = blockIdx.x * blockDim.x + threadIdx.x;
    if (i < N_NODES) { deg[i] = 1; cursor[i] = 0; }
    if (i < NUM_GRAPHS * HIDDEN) pooled[i] = 0.0f;
    if (i < NUM_GRAPHS) gcnt[i] = 0.0f;
}

// ---- in-degree (incl. self-loop via init=1) ----
__global__ void deg_count_kernel(const int* __restrict__ col, int* __restrict__ deg) {
    int e = blockIdx.x * blockDim.x + threadIdx.x;
    if (e < N_EDGES) atomicAdd(&deg[col[e]], 1);
}

// ---- exclusive scan of (deg-1) -> csr_off, single block ----
__global__ void scan_kernel(const int* __restrict__ deg, int* __restrict__ csr_off) {
    __shared__ int buf[1024];
    __shared__ int carry;
    int tid = threadIdx.x;
    if (tid == 0) carry = 0;
    __syncthreads();
    for (int base = 0; base < N_NODES; base += 1024) {
        int i = base + tid;
        int v = (i < N_NODES) ? (deg[i] - 1) : 0;
        buf[tid] = v;
        __syncthreads();
        for (int off = 1; off < 1024; off <<= 1) {
            int t = (tid >= off) ? buf[tid - off] : 0;
            __syncthreads();
            buf[tid] += t;
            __syncthreads();
        }
        int total = buf[1023];
        int excl  = buf[tid] - v;
        int c = carry;
        __syncthreads();
        if (i < N_NODES) csr_off[i] = c + excl;
        if (tid == 0) carry = c + total;
        __syncthreads();
    }
    if (tid == 0) csr_off[N_NODES] = carry;  // == N_EDGES
}

__global__ void dinv_kernel(const int* __restrict__ deg, float* __restrict__ dinv) {
    int i = blockIdx.x * blockDim.x + threadIdx.x;
    if (i < N_NODES) dinv[i] = 1.0f / sqrtf((float)deg[i]);
}

// ---- counting-sort edges by target; precompute per-edge norm ----
__global__ void scatter_kernel(const int* __restrict__ row, const int* __restrict__ col,
                               const int* __restrict__ csr_off, int* __restrict__ cursor,
                               const float* __restrict__ dinv,
                               int* __restrict__ csr_src, float* __restrict__ csr_norm) {
    int e = blockIdx.x * blockDim.x + threadIdx.x;
    if (e >= N_EDGES) return;
    int s = row[e], d = col[e];
    int pos = csr_off[d] + atomicAdd(&cursor[d], 1);
    csr_src[pos]  = s;
    csr_norm[pos] = dinv[s] * dinv[d];
}

// ---- AtomEncoder: h[n][d] = sum_f emb[x[n][f] + off[f]][d] ----
__global__ void encoder_kernel(const int* __restrict__ x, const float* __restrict__ emb,
                               float* __restrict__ h) {
    int n = blockIdx.x;
    int d = threadIdx.x;
    if (d >= HIDDEN) return;
    const int offs[9] = {0, 119, 124, 136, 148, 158, 164, 170, 172};
    float acc = 0.0f;
#pragma unroll
    for (int f = 0; f < 9; ++f) {
        int idx = x[n * 9 + f] + offs[f];
        acc += emb[idx * HIDDEN + d];
    }
    h[n * HIDDEN + d] = acc;
}

// ---- hw = h @ W  (W staged in LDS; one wave per row, lane covers d and d+64) ----
__global__ void matmul_kernel(const float* __restrict__ h, const float* __restrict__ W,
                              float* __restrict__ out) {
    __shared__ float Wl[HIDDEN * HIDDEN];
    int tid = threadIdx.x;
    for (int i = tid; i < HIDDEN * HIDDEN; i += 256) Wl[i] = W[i];
    __syncthreads();
    int lane = tid & 63;
    int gw = (blockIdx.x * 256 + tid) >> 6;
    int nw = (gridDim.x * 256) >> 6;
    int d1 = 64 + lane;
    bool has1 = (d1 < HIDDEN);
    for (int n = gw; n < N_NODES; n += nw) {
        float acc0 = 0.f, acc1 = 0.f;
        const float* hr = h + (size_t)n * HIDDEN;
#pragma unroll 4
        for (int k = 0; k < HIDDEN; ++k) {
            float hk = hr[k];
            acc0 += hk * Wl[k * HIDDEN + lane];
            if (has1) acc1 += hk * Wl[k * HIDDEN + d1];
        }
        out[(size_t)n * HIDDEN + lane] = acc0;
        if (has1) out[(size_t)n * HIDDEN + d1] = acc1;
    }
}

// ---- GCN aggregation: one wave per node, accumulators in registers ----
__global__ void agg_kernel(const float* __restrict__ hw, const int* __restrict__ csr_off,
                           const int* __restrict__ csr_src, const float* __restrict__ csr_norm,
                           const float* __restrict__ dinv, const int* __restrict__ deg,
                           const float* __restrict__ bias, float* __restrict__ out, int relu) {
    int wid  = (blockIdx.x * blockDim.x + threadIdx.x) >> 6;
    int lane = threadIdx.x & 63;
    if (wid >= N_NODES) return;
    int n = wid;
    int d1 = 64 + lane;
    bool has1 = (d1 < HIDDEN);

    float dn  = dinv[n];
    float nrm = dn * dn;  // self-loop norm
    float acc0 = invclip(nrm * hw[(size_t)n * HIDDEN + lane]);
    float acc1 = has1 ? invclip(nrm * hw[(size_t)n * HIDDEN + d1]) : 0.f;

    int beg = csr_off[n], end = csr_off[n + 1];
    for (int i = beg; i < end; ++i) {
        int s   = csr_src[i];
        float w = csr_norm[i];
        acc0 += invclip(w * hw[(size_t)s * HIDDEN + lane]);
        if (has1) acc1 += invclip(w * hw[(size_t)s * HIDDEN + d1]);
    }
    float cnt = (float)deg[n];  // messages per target (deg >= 1 always)
    float a0 = invclip(acc0 / cnt) + bias[lane];
    if (relu) a0 = fmaxf(a0, 0.f);
    out[(size_t)n * HIDDEN + lane] = a0;
    if (has1) {
        float a1 = invclip(acc1 / cnt) + bias[d1];
        if (relu) a1 = fmaxf(a1, 0.f);
        out[(size_t)n * HIDDEN + d1] = a1;
    }
}

// ---- global mean pool (sum via atomics; divide in final) ----
__global__ void pool_kernel(const float* __restrict__ h, const int* __restrict__ batch,
                            float* __restrict__ pooled, float* __restrict__ gcnt) {
    int n = blockIdx.x;
    int d = threadIdx.x;
    int g = batch[n];
    if (d < HIDDEN) atomicAdd(&pooled[(size_t)g * HIDDEN + d], h[(size_t)n * HIDDEN + d]);
    if (d == 0) atomicAdd(&gcnt[g], 1.0f);
}

// ---- out = (pooled/cnt) @ Wlin + blin ----
__global__ void final_kernel(const float* __restrict__ pooled, const float* __restrict__ gcnt,
                             const float* __restrict__ Wlin, const float* __restrict__ blin,
                             float* __restrict__ out) {
    int g = blockIdx.x;
    int t = threadIdx.x;  // 128 = NUM_TASKS
    float inv = 1.0f / fmaxf(gcnt[g], 1.0f);
    float acc = 0.f;
#pragma unroll 4
    for (int j = 0; j < HIDDEN; ++j)
        acc += pooled[(size_t)g * HIDDEN + j] * Wlin[j * NUM_TASKS + t];
    out[(size_t)g * NUM_TASKS + t] = acc * inv + blin[t];
}

extern "C" void kernel_launch(void* const* d_in, const int* in_sizes, int n_in,
                              void* d_out, int out_size, void* d_ws, size_t ws_size,
                              hipStream_t stream) {
    const int*   x     = (const int*)d_in[0];
    const int*   ei    = (const int*)d_in[1];
    const int*   batch = (const int*)d_in[2];
    const float* emb   = (const float*)d_in[3];
    const float* W1    = (const float*)d_in[4];
    const float* b1    = (const float*)d_in[5];
    const float* W2    = (const float*)d_in[6];
    const float* b2    = (const float*)d_in[7];
    const float* Wlin  = (const float*)d_in[8];
    const float* blin  = (const float*)d_in[9];
    float* out = (float*)d_out;

    const int* row = ei;             // edge_index[0] = source
    const int* col = ei + N_EDGES;   // edge_index[1] = target

    // carve workspace (256B-aligned chunks)
    char* ws = (char*)d_ws;
    auto alloc = [&](size_t bytes) -> char* {
        char* p = ws;
        ws += (bytes + 255) & ~(size_t)255;
        return p;
    };
    int*   deg      = (int*)  alloc((size_t)N_NODES * 4);
    int*   cursor   = (int*)  alloc((size_t)N_NODES * 4);
    int*   csr_off  = (int*)  alloc((size_t)(N_NODES + 1) * 4);
    float* dinv     = (float*)alloc((size_t)N_NODES * 4);
    int*   csr_src  = (int*)  alloc((size_t)N_EDGES * 4);
    float* csr_norm = (float*)alloc((size_t)N_EDGES * 4);
    float* bufA     = (float*)alloc((size_t)N_NODES * HIDDEN * 4);
    float* bufB     = (float*)alloc((size_t)N_NODES * HIDDEN * 4);
    float* pooled   = (float*)alloc((size_t)NUM_GRAPHS * HIDDEN * 4);
    float* gcnt     = (float*)alloc((size_t)NUM_GRAPHS * 4);

    init_kernel<<<(NUM_GRAPHS * HIDDEN + 255) / 256, 256, 0, stream>>>(deg, cursor, pooled, gcnt);
    deg_count_kernel<<<(N_EDGES + 255) / 256, 256, 0, stream>>>(col, deg);
    scan_kernel<<<1, 1024, 0, stream>>>(deg, csr_off);
    dinv_kernel<<<(N_NODES + 255) / 256, 256, 0, stream>>>(deg, dinv);
    scatter_kernel<<<(N_EDGES + 255) / 256, 256, 0, stream>>>(row, col, csr_off, cursor, dinv,
                                                              csr_src, csr_norm);
    encoder_kernel<<<N_NODES, 128, 0, stream>>>(x, emb, bufA);

    // conv1: hw = h0 @ W1 ; agg -> relu -> h1
    matmul_kernel<<<512, 256, 0, stream>>>(bufA, W1, bufB);
    agg_kernel<<<(N_NODES + 3) / 4, 256, 0, stream>>>(bufB, csr_off, csr_src, csr_norm,
                                                      dinv, deg, b1, bufA, 1);
    // conv2
    matmul_kernel<<<512, 256, 0, stream>>>(bufA, W2, bufB);
    agg_kernel<<<(N_NODES + 3) / 4, 256, 0, stream>>>(bufB, csr_off, csr_src, csr_norm,
                                                      dinv, deg, b2, bufA, 0);

    pool_kernel<<<N_NODES, 128, 0, stream>>>(bufA, batch, pooled, gcnt);
    final_kernel<<<NUM_GRAPHS, 128, 0, stream>>>(pooled, gcnt, Wlin, blin, out);
}

// Round 2
// 414.372 us; speedup vs baseline: 2.2098x; 2.2098x over previous
//
#include <hip/hip_runtime.h>

#define N_NODES   50000
#define N_EDGES   800000
#define HIDDEN    100
#define NUM_TASKS 128
#define NUM_GRAPHS 2000
#define EPS 1e-16f

static __device__ __forceinline__ float invclip(float v) {
    // clip(v, EPS, 100) ** -1
    return 1.0f / fminf(fmaxf(v, EPS), 100.0f);
}

// ---- init: deg=1 (self loop), cursor=0 ----
__global__ void init_kernel(int* __restrict__ deg, int* __restrict__ cursor) {
    int i = blockIdx.x * blockDim.x + threadIdx.x;
    if (i < N_NODES) { deg[i] = 1; cursor[i] = 0; }
}

// ---- in-degree (incl. self-loop via init=1) ----
__global__ void deg_count_kernel(const int* __restrict__ col, int* __restrict__ deg) {
    int e = blockIdx.x * blockDim.x + threadIdx.x;
    if (e < N_EDGES) atomicAdd(&deg[col[e]], 1);
}

// ---- hierarchical exclusive scan of (deg-1) -> csr_off ----
__global__ void blk_sum_kernel(const int* __restrict__ deg, int* __restrict__ bsum) {
    int i = blockIdx.x * 256 + threadIdx.x;
    int v = (i < N_NODES) ? (deg[i] - 1) : 0;
#pragma unroll
    for (int off = 32; off > 0; off >>= 1) v += __shfl_down(v, off, 64);
    __shared__ int ws[4];
    if ((threadIdx.x & 63) == 0) ws[threadIdx.x >> 6] = v;
    __syncthreads();
    if (threadIdx.x == 0) bsum[blockIdx.x] = ws[0] + ws[1] + ws[2] + ws[3];
}

__global__ void bsum_scan_kernel(int* __restrict__ bsum, int nblk) {
    __shared__ int buf[256];
    int t = threadIdx.x;
    int v = (t < nblk) ? bsum[t] : 0;
    buf[t] = v;
    __syncthreads();
    for (int off = 1; off < 256; off <<= 1) {
        int x = (t >= off) ? buf[t - off] : 0;
        __syncthreads();
        buf[t] += x;
        __syncthreads();
    }
    if (t < nblk) bsum[t] = buf[t] - v;  // exclusive base per block
}

__global__ void blk_scan_kernel(const int* __restrict__ deg, const int* __restrict__ bbase,
                                int* __restrict__ csr_off) {
    __shared__ int buf[256];
    int t = threadIdx.x;
    int i = blockIdx.x * 256 + t;
    int v = (i < N_NODES) ? (deg[i] - 1) : 0;
    buf[t] = v;
    __syncthreads();
    for (int off = 1; off < 256; off <<= 1) {
        int x = (t >= off) ? buf[t - off] : 0;
        __syncthreads();
        buf[t] += x;
        __syncthreads();
    }
    if (i < N_NODES) csr_off[i] = bbase[blockIdx.x] + buf[t] - v;
    else if (i == N_NODES) csr_off[N_NODES] = N_EDGES;
}

__global__ void dinv_kernel(const int* __restrict__ deg, float* __restrict__ dinv) {
    int i = blockIdx.x * blockDim.x + threadIdx.x;
    if (i < N_NODES) dinv[i] = 1.0f / sqrtf((float)deg[i]);
}

// ---- counting-sort edges by target; precompute per-edge norm ----
__global__ void scatter_kernel(const int* __restrict__ row, const int* __restrict__ col,
                               const int* __restrict__ csr_off, int* __restrict__ cursor,
                               const float* __restrict__ dinv,
                               int* __restrict__ csr_src, float* __restrict__ csr_norm) {
    int e = blockIdx.x * blockDim.x + threadIdx.x;
    if (e >= N_EDGES) return;
    int s = row[e], d = col[e];
    int pos = csr_off[d] + atomicAdd(&cursor[d], 1);
    csr_src[pos]  = s;
    csr_norm[pos] = dinv[s] * dinv[d];
}

// ---- AtomEncoder: h[n][d] = sum_f emb[x[n][f] + off[f]][d] ----
__global__ void encoder_kernel(const int* __restrict__ x, const float* __restrict__ emb,
                               float* __restrict__ h) {
    int n = blockIdx.x;
    int d = threadIdx.x;
    if (d >= HIDDEN) return;
    const int offs[9] = {0, 119, 124, 136, 148, 158, 164, 170, 172};
    float acc = 0.0f;
#pragma unroll
    for (int f = 0; f < 9; ++f) {
        int idx = x[n * 9 + f] + offs[f];
        acc += emb[idx * HIDDEN + d];
    }
    h[n * HIDDEN + d] = acc;
}

// ---- tiled matmul: 64-node tile, W + h-tile in LDS, 4x4 register tile ----
// thread (tx,ty): tx in [0,32) owns dims {4tx..4tx+3} (active tx<25),
// ty in [0,16) owns nodes {ty, ty+16, ty+32, ty+48}.
#define MM_NODES 64
#define WL_PAD   10032   // 100*100 + pad so tx>=25 garbage reads stay in-array
__global__ __launch_bounds__(512) void matmul_kernel(const float* __restrict__ h,
                                                     const float* __restrict__ W,
                                                     float* __restrict__ out) {
    __shared__ float Wl[WL_PAD];
    __shared__ float hl[MM_NODES * HIDDEN];
    int tid = threadIdx.x;
    int nb = blockIdx.x * MM_NODES;

    for (int i = tid; i < WL_PAD; i += 512)
        Wl[i] = (i < HIDDEN * HIDDEN) ? W[i] : 0.0f;
    for (int i = tid; i < MM_NODES * HIDDEN; i += 512) {
        int n = i / HIDDEN;
        hl[i] = (nb + n < N_NODES) ? h[(size_t)(nb + n) * HIDDEN + (i % HIDDEN)] : 0.0f;
    }
    __syncthreads();

    int tx = tid & 31;
    int ty = tid >> 5;  // 0..15

    float4 acc[4];
#pragma unroll
    for (int jn = 0; jn < 4; ++jn) acc[jn] = make_float4(0.f, 0.f, 0.f, 0.f);

    for (int kk = 0; kk < HIDDEN; kk += 4) {
        float hs[4][4];
#pragma unroll
        for (int jn = 0; jn < 4; ++jn) {
            float4 hv = *(const float4*)&hl[(ty + 16 * jn) * HIDDEN + kk];
            hs[jn][0] = hv.x; hs[jn][1] = hv.y; hs[jn][2] = hv.z; hs[jn][3] = hv.w;
        }
#pragma unroll
        for (int dk = 0; dk < 4; ++dk) {
            float4 wv = *(const float4*)&Wl[(kk + dk) * HIDDEN + 4 * tx];
#pragma unroll
            for (int jn = 0; jn < 4; ++jn) {
                acc[jn].x += hs[jn][dk] * wv.x;
                acc[jn].y += hs[jn][dk] * wv.y;
                acc[jn].z += hs[jn][dk] * wv.z;
                acc[jn].w += hs[jn][dk] * wv.w;
            }
        }
    }

    if (tx < 25) {  // 4*tx+3 <= 99
#pragma unroll
        for (int jn = 0; jn < 4; ++jn) {
            int n = nb + ty + 16 * jn;
            if (n < N_NODES)
                *(float4*)&out[(size_t)n * HIDDEN + 4 * tx] = acc[jn];
        }
    }
}

// ---- GCN aggregation: one wave per node, accumulators in registers ----
__global__ void agg_kernel(const float* __restrict__ hw, const int* __restrict__ csr_off,
                           const int* __restrict__ csr_src, const float* __restrict__ csr_norm,
                           const float* __restrict__ dinv, const int* __restrict__ deg,
                           const float* __restrict__ bias, float* __restrict__ out, int relu) {
    int wid  = (blockIdx.x * blockDim.x + threadIdx.x) >> 6;
    int lane = threadIdx.x & 63;
    if (wid >= N_NODES) return;
    int n = wid;
    int d1 = 64 + lane;
    bool has1 = (d1 < HIDDEN);

    float dn  = dinv[n];
    float nrm = dn * dn;  // self-loop norm
    float acc0 = invclip(nrm * hw[(size_t)n * HIDDEN + lane]);
    float acc1 = has1 ? invclip(nrm * hw[(size_t)n * HIDDEN + d1]) : 0.f;

    int beg = csr_off[n], end = csr_off[n + 1];
    for (int i = beg; i < end; ++i) {
        int s   = csr_src[i];
        float w = csr_norm[i];
        acc0 += invclip(w * hw[(size_t)s * HIDDEN + lane]);
        if (has1) acc1 += invclip(w * hw[(size_t)s * HIDDEN + d1]);
    }
    float cnt = (float)deg[n];  // messages per target (deg >= 1 always)
    float a0 = invclip(acc0 / cnt) + bias[lane];
    if (relu) a0 = fmaxf(a0, 0.f);
    out[(size_t)n * HIDDEN + lane] = a0;
    if (has1) {
        float a1 = invclip(acc1 / cnt) + bias[d1];
        if (relu) a1 = fmaxf(a1, 0.f);
        out[(size_t)n * HIDDEN + d1] = a1;
    }
}

// ---- fused mean-pool + linear head (batch is sorted -> binary search range) ----
__global__ void pool_final_kernel(const float* __restrict__ h, const int* __restrict__ batch,
                                  const float* __restrict__ Wlin, const float* __restrict__ blin,
                                  float* __restrict__ out) {
    int g = blockIdx.x;
    int t = threadIdx.x;  // 128 = NUM_TASKS
    __shared__ float pl[HIDDEN];

    // lower_bound(g) and lower_bound(g+1) over sorted batch (uniform per block)
    int lo = 0, hi = N_NODES;
    while (lo < hi) { int mid = (lo + hi) >> 1; if (batch[mid] < g) lo = mid + 1; else hi = mid; }
    int start = lo;
    hi = N_NODES;
    while (lo < hi) { int mid = (lo + hi) >> 1; if (batch[mid] < g + 1) lo = mid + 1; else hi = mid; }
    int end = lo;

    float inv = 1.0f / fmaxf((float)(end - start), 1.0f);
    if (t < HIDDEN) {
        float acc = 0.f;
        for (int n = start; n < end; ++n) acc += h[(size_t)n * HIDDEN + t];
        pl[t] = acc * inv;
    }
    __syncthreads();

    float o = 0.f;
#pragma unroll 4
    for (int j = 0; j < HIDDEN; ++j) o += pl[j] * Wlin[j * NUM_TASKS + t];
    out[(size_t)g * NUM_TASKS + t] = o + blin[t];
}

extern "C" void kernel_launch(void* const* d_in, const int* in_sizes, int n_in,
                              void* d_out, int out_size, void* d_ws, size_t ws_size,
                              hipStream_t stream) {
    const int*   x     = (const int*)d_in[0];
    const int*   ei    = (const int*)d_in[1];
    const int*   batch = (const int*)d_in[2];
    const float* emb   = (const float*)d_in[3];
    const float* W1    = (const float*)d_in[4];
    const float* b1    = (const float*)d_in[5];
    const float* W2    = (const float*)d_in[6];
    const float* b2    = (const float*)d_in[7];
    const float* Wlin  = (const float*)d_in[8];
    const float* blin  = (const float*)d_in[9];
    float* out = (float*)d_out;

    const int* row = ei;             // edge_index[0] = source
    const int* col = ei + N_EDGES;   // edge_index[1] = target

    char* ws = (char*)d_ws;
    auto alloc = [&](size_t bytes) -> char* {
        char* p = ws;
        ws += (bytes + 255) & ~(size_t)255;
        return p;
    };
    int*   deg      = (int*)  alloc((size_t)N_NODES * 4);
    int*   cursor   = (int*)  alloc((size_t)N_NODES * 4);
    int*   csr_off  = (int*)  alloc((size_t)(N_NODES + 1) * 4);
    float* dinv     = (float*)alloc((size_t)N_NODES * 4);
    int*   csr_src  = (int*)  alloc((size_t)N_EDGES * 4);
    float* csr_norm = (float*)alloc((size_t)N_EDGES * 4);
    float* bufA     = (float*)alloc((size_t)N_NODES * HIDDEN * 4);
    float* bufB     = (float*)alloc((size_t)N_NODES * HIDDEN * 4);
    int*   bsum     = (int*)  alloc(256 * 4);

    const int SCAN_BLOCKS = (N_NODES + 255) / 256;  // 196

    init_kernel<<<(N_NODES + 255) / 256, 256, 0, stream>>>(deg, cursor);
    deg_count_kernel<<<(N_EDGES + 255) / 256, 256, 0, stream>>>(col, deg);
    blk_sum_kernel<<<SCAN_BLOCKS, 256, 0, stream>>>(deg, bsum);
    bsum_scan_kernel<<<1, 256, 0, stream>>>(bsum, SCAN_BLOCKS);
    blk_scan_kernel<<<SCAN_BLOCKS, 256, 0, stream>>>(deg, bsum, csr_off);
    dinv_kernel<<<(N_NODES + 255) / 256, 256, 0, stream>>>(deg, dinv);
    scatter_kernel<<<(N_EDGES + 255) / 256, 256, 0, stream>>>(row, col, csr_off, cursor, dinv,
                                                              csr_src, csr_norm);
    encoder_kernel<<<N_NODES, 128, 0, stream>>>(x, emb, bufA);

    const int MM_BLOCKS = (N_NODES + MM_NODES - 1) / MM_NODES;  // 782
    // conv1: hw = h0 @ W1 ; agg -> relu -> h1
    matmul_kernel<<<MM_BLOCKS, 512, 0, stream>>>(bufA, W1, bufB);
    agg_kernel<<<(N_NODES + 3) / 4, 256, 0, stream>>>(bufB, csr_off, csr_src, csr_norm,
                                                      dinv, deg, b1, bufA, 1);
    // conv2
    matmul_kernel<<<MM_BLOCKS, 512, 0, stream>>>(bufA, W2, bufB);
    agg_kernel<<<(N_NODES + 3) / 4, 256, 0, stream>>>(bufB, csr_off, csr_src, csr_norm,
                                                      dinv, deg, b2, bufA, 0);

    pool_final_kernel<<<NUM_GRAPHS, 128, 0, stream>>>(bufA, batch, Wlin, blin, out);
}

// Round 3
// 334.153 us; speedup vs baseline: 2.7403x; 1.2401x over previous
//
#include <hip/hip_runtime.h>

#define N_NODES   50000
#define N_EDGES   800000
#define HIDDEN    100
#define NUM_TASKS 128
#define NUM_GRAPHS 2000
#define EPS 1e-16f

static __device__ __forceinline__ float rcp_fast(float v) {
    return __builtin_amdgcn_rcpf(v);  // 1-ulp v_rcp_f32
}
static __device__ __forceinline__ float invclip(float v) {
    // clip(v, EPS, 100) ** -1
    return rcp_fast(fminf(fmaxf(v, EPS), 100.0f));
}

// ---- init: deg=1 (self loop), cursor=0 ----
__global__ void init_kernel(int* __restrict__ deg, int* __restrict__ cursor) {
    int i = blockIdx.x * blockDim.x + threadIdx.x;
    if (i < N_NODES) { deg[i] = 1; cursor[i] = 0; }
}

// ---- in-degree (incl. self-loop via init=1) ----
__global__ void deg_count_kernel(const int* __restrict__ col, int* __restrict__ deg) {
    int e = blockIdx.x * blockDim.x + threadIdx.x;
    if (e < N_EDGES) atomicAdd(&deg[col[e]], 1);
}

// ---- hierarchical exclusive scan of (deg-1) -> csr_off ----
__global__ void blk_sum_kernel(const int* __restrict__ deg, int* __restrict__ bsum) {
    int i = blockIdx.x * 256 + threadIdx.x;
    int v = (i < N_NODES) ? (deg[i] - 1) : 0;
#pragma unroll
    for (int off = 32; off > 0; off >>= 1) v += __shfl_down(v, off, 64);
    __shared__ int ws[4];
    if ((threadIdx.x & 63) == 0) ws[threadIdx.x >> 6] = v;
    __syncthreads();
    if (threadIdx.x == 0) bsum[blockIdx.x] = ws[0] + ws[1] + ws[2] + ws[3];
}

__global__ void bsum_scan_kernel(int* __restrict__ bsum, int nblk) {
    __shared__ int buf[256];
    int t = threadIdx.x;
    int v = (t < nblk) ? bsum[t] : 0;
    buf[t] = v;
    __syncthreads();
    for (int off = 1; off < 256; off <<= 1) {
        int x = (t >= off) ? buf[t - off] : 0;
        __syncthreads();
        buf[t] += x;
        __syncthreads();
    }
    if (t < nblk) bsum[t] = buf[t] - v;  // exclusive base per block
}

__global__ void blk_scan_kernel(const int* __restrict__ deg, const int* __restrict__ bbase,
                                int* __restrict__ csr_off) {
    __shared__ int buf[256];
    int t = threadIdx.x;
    int i = blockIdx.x * 256 + t;
    int v = (i < N_NODES) ? (deg[i] - 1) : 0;
    buf[t] = v;
    __syncthreads();
    for (int off = 1; off < 256; off <<= 1) {
        int x = (t >= off) ? buf[t - off] : 0;
        __syncthreads();
        buf[t] += x;
        __syncthreads();
    }
    if (i < N_NODES) csr_off[i] = bbase[blockIdx.x] + buf[t] - v;
    else if (i == N_NODES) csr_off[N_NODES] = N_EDGES;
}

__global__ void dinv_kernel(const int* __restrict__ deg, float* __restrict__ dinv) {
    int i = blockIdx.x * blockDim.x + threadIdx.x;
    if (i < N_NODES) dinv[i] = 1.0f / sqrtf((float)deg[i]);
}

// ---- counting-sort edges by target; pack (src, norm) per slot ----
__global__ void scatter_kernel(const int* __restrict__ row, const int* __restrict__ col,
                               const int* __restrict__ csr_off, int* __restrict__ cursor,
                               const float* __restrict__ dinv, int2* __restrict__ csr_pack) {
    int e = blockIdx.x * blockDim.x + threadIdx.x;
    if (e >= N_EDGES) return;
    int s = row[e], d = col[e];
    int pos = csr_off[d] + atomicAdd(&cursor[d], 1);
    int2 p;
    p.x = s;
    p.y = __float_as_int(dinv[s] * dinv[d]);
    csr_pack[pos] = p;
}

// ---- AtomEncoder: h[n][d] = sum_f emb[x[n][f] + off[f]][d] ----
__global__ void encoder_kernel(const int* __restrict__ x, const float* __restrict__ emb,
                               float* __restrict__ h) {
    int n = blockIdx.x;
    int d = threadIdx.x;
    if (d >= HIDDEN) return;
    const int offs[9] = {0, 119, 124, 136, 148, 158, 164, 170, 172};
    float acc = 0.0f;
#pragma unroll
    for (int f = 0; f < 9; ++f) {
        int idx = x[n * 9 + f] + offs[f];
        acc += emb[idx * HIDDEN + d];
    }
    h[n * HIDDEN + d] = acc;
}

// ---- tiled matmul: 64-node tile, W + h-tile in LDS, 4x4 register tile ----
#define MM_NODES 64
#define WL_PAD   10032
__global__ __launch_bounds__(512) void matmul_kernel(const float* __restrict__ h,
                                                     const float* __restrict__ W,
                                                     float* __restrict__ out) {
    __shared__ float Wl[WL_PAD];
    __shared__ float hl[MM_NODES * HIDDEN];
    int tid = threadIdx.x;
    int nb = blockIdx.x * MM_NODES;

    for (int i = tid; i < WL_PAD; i += 512)
        Wl[i] = (i < HIDDEN * HIDDEN) ? W[i] : 0.0f;
    for (int i = tid; i < MM_NODES * HIDDEN; i += 512) {
        int n = i / HIDDEN;
        hl[i] = (nb + n < N_NODES) ? h[(size_t)(nb + n) * HIDDEN + (i % HIDDEN)] : 0.0f;
    }
    __syncthreads();

    int tx = tid & 31;
    int ty = tid >> 5;  // 0..15

    float4 acc[4];
#pragma unroll
    for (int jn = 0; jn < 4; ++jn) acc[jn] = make_float4(0.f, 0.f, 0.f, 0.f);

    for (int kk = 0; kk < HIDDEN; kk += 4) {
        float hs[4][4];
#pragma unroll
        for (int jn = 0; jn < 4; ++jn) {
            float4 hv = *(const float4*)&hl[(ty + 16 * jn) * HIDDEN + kk];
            hs[jn][0] = hv.x; hs[jn][1] = hv.y; hs[jn][2] = hv.z; hs[jn][3] = hv.w;
        }
#pragma unroll
        for (int dk = 0; dk < 4; ++dk) {
            float4 wv = *(const float4*)&Wl[(kk + dk) * HIDDEN + 4 * tx];
#pragma unroll
            for (int jn = 0; jn < 4; ++jn) {
                acc[jn].x += hs[jn][dk] * wv.x;
                acc[jn].y += hs[jn][dk] * wv.y;
                acc[jn].z += hs[jn][dk] * wv.z;
                acc[jn].w += hs[jn][dk] * wv.w;
            }
        }
    }

    if (tx < 25) {
#pragma unroll
        for (int jn = 0; jn < 4; ++jn) {
            int n = nb + ty + 16 * jn;
            if (n < N_NODES)
                *(float4*)&out[(size_t)n * HIDDEN + 4 * tx] = acc[jn];
        }
    }
}

// ---- GCN aggregation: wave per node, float2 lanes, unroll-4 prefetch ----
__global__ __launch_bounds__(256) void agg_kernel(
        const float* __restrict__ hw, const int* __restrict__ csr_off,
        const int2* __restrict__ csr_pack, const float* __restrict__ dinv,
        const int* __restrict__ deg, const float* __restrict__ bias,
        float* __restrict__ out, int relu) {
    int wid  = (blockIdx.x * blockDim.x + threadIdx.x) >> 6;
    int lane = threadIdx.x & 63;
    if (wid >= N_NODES) return;
    int n = wid;
    bool act = lane < 50;  // lane owns dims 2*lane, 2*lane+1
    const float2* hw2 = (const float2*)hw;
    size_t loff = 50 * (size_t)0 + lane;  // silence unused warn pattern

    float dn  = dinv[n];
    float nrm = dn * dn;  // self-loop norm
    float2 acc;
    {
        float2 v = act ? hw2[(size_t)n * 50 + lane] : make_float2(1.f, 1.f);
        acc.x = invclip(nrm * v.x);
        acc.y = invclip(nrm * v.y);
    }

    int beg = csr_off[n], end = csr_off[n + 1];
    int i = beg;
    for (; i + 4 <= end; i += 4) {
        int2 p0 = csr_pack[i];
        int2 p1 = csr_pack[i + 1];
        int2 p2 = csr_pack[i + 2];
        int2 p3 = csr_pack[i + 3];
        float2 v0 = act ? hw2[(size_t)p0.x * 50 + lane] : make_float2(1.f, 1.f);
        float2 v1 = act ? hw2[(size_t)p1.x * 50 + lane] : make_float2(1.f, 1.f);
        float2 v2 = act ? hw2[(size_t)p2.x * 50 + lane] : make_float2(1.f, 1.f);
        float2 v3 = act ? hw2[(size_t)p3.x * 50 + lane] : make_float2(1.f, 1.f);
        float w0 = __int_as_float(p0.y), w1 = __int_as_float(p1.y);
        float w2 = __int_as_float(p2.y), w3 = __int_as_float(p3.y);
        acc.x += invclip(w0 * v0.x); acc.y += invclip(w0 * v0.y);
        acc.x += invclip(w1 * v1.x); acc.y += invclip(w1 * v1.y);
        acc.x += invclip(w2 * v2.x); acc.y += invclip(w2 * v2.y);
        acc.x += invclip(w3 * v3.x); acc.y += invclip(w3 * v3.y);
    }
    for (; i < end; ++i) {
        int2 p = csr_pack[i];
        float2 v = act ? hw2[(size_t)p.x * 50 + lane] : make_float2(1.f, 1.f);
        float w = __int_as_float(p.y);
        acc.x += invclip(w * v.x);
        acc.y += invclip(w * v.y);
    }

    float rcnt = rcp_fast((float)deg[n]);  // messages per target
    if (act) {
        float2 o;
        o.x = invclip(acc.x * rcnt) + bias[2 * lane];
        o.y = invclip(acc.y * rcnt) + bias[2 * lane + 1];
        if (relu) { o.x = fmaxf(o.x, 0.f); o.y = fmaxf(o.y, 0.f); }
        *(float2*)&out[(size_t)n * HIDDEN + 2 * lane] = o;
    }
    (void)loff;
}

// ---- fused mean-pool + linear head (batch sorted -> binary search range) ----
__global__ void pool_final_kernel(const float* __restrict__ h, const int* __restrict__ batch,
                                  const float* __restrict__ Wlin, const float* __restrict__ blin,
                                  float* __restrict__ out) {
    int g = blockIdx.x;
    int t = threadIdx.x;  // 128 = NUM_TASKS
    __shared__ float pl[HIDDEN];

    int lo = 0, hi = N_NODES;
    while (lo < hi) { int mid = (lo + hi) >> 1; if (batch[mid] < g) lo = mid + 1; else hi = mid; }
    int start = lo;
    hi = N_NODES;
    while (lo < hi) { int mid = (lo + hi) >> 1; if (batch[mid] < g + 1) lo = mid + 1; else hi = mid; }
    int end = lo;

    float inv = 1.0f / fmaxf((float)(end - start), 1.0f);
    if (t < HIDDEN) {
        float acc = 0.f;
        for (int n = start; n < end; ++n) acc += h[(size_t)n * HIDDEN + t];
        pl[t] = acc * inv;
    }
    __syncthreads();

    float o = 0.f;
#pragma unroll 4
    for (int j = 0; j < HIDDEN; ++j) o += pl[j] * Wlin[j * NUM_TASKS + t];
    out[(size_t)g * NUM_TASKS + t] = o + blin[t];
}

extern "C" void kernel_launch(void* const* d_in, const int* in_sizes, int n_in,
                              void* d_out, int out_size, void* d_ws, size_t ws_size,
                              hipStream_t stream) {
    const int*   x     = (const int*)d_in[0];
    const int*   ei    = (const int*)d_in[1];
    const int*   batch = (const int*)d_in[2];
    const float* emb   = (const float*)d_in[3];
    const float* W1    = (const float*)d_in[4];
    const float* b1    = (const float*)d_in[5];
    const float* W2    = (const float*)d_in[6];
    const float* b2    = (const float*)d_in[7];
    const float* Wlin  = (const float*)d_in[8];
    const float* blin  = (const float*)d_in[9];
    float* out = (float*)d_out;

    const int* row = ei;             // edge_index[0] = source
    const int* col = ei + N_EDGES;   // edge_index[1] = target

    char* ws = (char*)d_ws;
    auto alloc = [&](size_t bytes) -> char* {
        char* p = ws;
        ws += (bytes + 255) & ~(size_t)255;
        return p;
    };
    int*   deg      = (int*)  alloc((size_t)N_NODES * 4);
    int*   cursor   = (int*)  alloc((size_t)N_NODES * 4);
    int*   csr_off  = (int*)  alloc((size_t)(N_NODES + 1) * 4);
    float* dinv     = (float*)alloc((size_t)N_NODES * 4);
    int2*  csr_pack = (int2*) alloc((size_t)N_EDGES * 8);
    float* bufA     = (float*)alloc((size_t)N_NODES * HIDDEN * 4);
    float* bufB     = (float*)alloc((size_t)N_NODES * HIDDEN * 4);
    int*   bsum     = (int*)  alloc(256 * 4);

    const int SCAN_BLOCKS = (N_NODES + 255) / 256;  // 196

    init_kernel<<<(N_NODES + 255) / 256, 256, 0, stream>>>(deg, cursor);
    deg_count_kernel<<<(N_EDGES + 255) / 256, 256, 0, stream>>>(col, deg);
    blk_sum_kernel<<<SCAN_BLOCKS, 256, 0, stream>>>(deg, bsum);
    bsum_scan_kernel<<<1, 256, 0, stream>>>(bsum, SCAN_BLOCKS);
    blk_scan_kernel<<<SCAN_BLOCKS, 256, 0, stream>>>(deg, bsum, csr_off);
    dinv_kernel<<<(N_NODES + 255) / 256, 256, 0, stream>>>(deg, dinv);
    scatter_kernel<<<(N_EDGES + 255) / 256, 256, 0, stream>>>(row, col, csr_off, cursor, dinv,
                                                              csr_pack);
    encoder_kernel<<<N_NODES, 128, 0, stream>>>(x, emb, bufA);

    const int MM_BLOCKS = (N_NODES + MM_NODES - 1) / MM_NODES;  // 782
    // conv1: hw = h0 @ W1 ; agg -> relu -> h1
    matmul_kernel<<<MM_BLOCKS, 512, 0, stream>>>(bufA, W1, bufB);
    agg_kernel<<<(N_NODES + 3) / 4, 256, 0, stream>>>(bufB, csr_off, csr_pack,
                                                      dinv, deg, b1, bufA, 1);
    // conv2
    matmul_kernel<<<MM_BLOCKS, 512, 0, stream>>>(bufA, W2, bufB);
    agg_kernel<<<(N_NODES + 3) / 4, 256, 0, stream>>>(bufB, csr_off, csr_pack,
                                                      dinv, deg, b2, bufA, 0);

    pool_final_kernel<<<NUM_GRAPHS, 128, 0, stream>>>(bufA, batch, Wlin, blin, out);
}

// Round 4
// 323.194 us; speedup vs baseline: 2.8332x; 1.0339x over previous
//
#include <hip/hip_runtime.h>

#define N_NODES   50000
#define N_EDGES   800000
#define HIDDEN    100
#define NUM_TASKS 128
#define NUM_GRAPHS 2000
#define EPS 1e-16f

static __device__ __forceinline__ float rcp_fast(float v) {
    return __builtin_amdgcn_rcpf(v);  // 1-ulp v_rcp_f32
}
static __device__ __forceinline__ float invclip(float v) {
    // clip(v, EPS, 100) ** -1
    return rcp_fast(fminf(fmaxf(v, EPS), 100.0f));
}

// ---- init: deg=1 (self loop), cursor=0 ----
__global__ void init_kernel(int* __restrict__ deg, int* __restrict__ cursor) {
    int i = blockIdx.x * blockDim.x + threadIdx.x;
    if (i < N_NODES) { deg[i] = 1; cursor[i] = 0; }
}

// ---- in-degree (incl. self-loop via init=1) ----
__global__ void deg_count_kernel(const int* __restrict__ col, int* __restrict__ deg) {
    int e = blockIdx.x * blockDim.x + threadIdx.x;
    if (e < N_EDGES) atomicAdd(&deg[col[e]], 1);
}

// ---- hierarchical exclusive scan of (deg-1) -> csr_off ----
__global__ void blk_sum_kernel(const int* __restrict__ deg, int* __restrict__ bsum) {
    int i = blockIdx.x * 256 + threadIdx.x;
    int v = (i < N_NODES) ? (deg[i] - 1) : 0;
#pragma unroll
    for (int off = 32; off > 0; off >>= 1) v += __shfl_down(v, off, 64);
    __shared__ int ws[4];
    if ((threadIdx.x & 63) == 0) ws[threadIdx.x >> 6] = v;
    __syncthreads();
    if (threadIdx.x == 0) bsum[blockIdx.x] = ws[0] + ws[1] + ws[2] + ws[3];
}

__global__ void bsum_scan_kernel(int* __restrict__ bsum, int nblk) {
    __shared__ int buf[256];
    int t = threadIdx.x;
    int v = (t < nblk) ? bsum[t] : 0;
    buf[t] = v;
    __syncthreads();
    for (int off = 1; off < 256; off <<= 1) {
        int x = (t >= off) ? buf[t - off] : 0;
        __syncthreads();
        buf[t] += x;
        __syncthreads();
    }
    if (t < nblk) bsum[t] = buf[t] - v;  // exclusive base per block
}

__global__ void blk_scan_kernel(const int* __restrict__ deg, const int* __restrict__ bbase,
                                int* __restrict__ csr_off) {
    __shared__ int buf[256];
    int t = threadIdx.x;
    int i = blockIdx.x * 256 + t;
    int v = (i < N_NODES) ? (deg[i] - 1) : 0;
    buf[t] = v;
    __syncthreads();
    for (int off = 1; off < 256; off <<= 1) {
        int x = (t >= off) ? buf[t - off] : 0;
        __syncthreads();
        buf[t] += x;
        __syncthreads();
    }
    if (i < N_NODES) csr_off[i] = bbase[blockIdx.x] + buf[t] - v;
    else if (i == N_NODES) csr_off[N_NODES] = N_EDGES;
}

__global__ void dinv_kernel(const int* __restrict__ deg, float* __restrict__ dinv) {
    int i = blockIdx.x * blockDim.x + threadIdx.x;
    if (i < N_NODES) dinv[i] = 1.0f / sqrtf((float)deg[i]);
}

// ---- counting-sort edges by target; pack (src, norm) per slot ----
__global__ void scatter_kernel(const int* __restrict__ row, const int* __restrict__ col,
                               const int* __restrict__ csr_off, int* __restrict__ cursor,
                               const float* __restrict__ dinv, int2* __restrict__ csr_pack) {
    int e = blockIdx.x * blockDim.x + threadIdx.x;
    if (e >= N_EDGES) return;
    int s = row[e], d = col[e];
    int pos = csr_off[d] + atomicAdd(&cursor[d], 1);
    int2 p;
    p.x = s;
    p.y = __float_as_int(dinv[s] * dinv[d]);
    csr_pack[pos] = p;
}

// ---- AtomEncoder: h[n][d] = sum_f emb[x[n][f] + off[f]][d] ----
__global__ void encoder_kernel(const int* __restrict__ x, const float* __restrict__ emb,
                               float* __restrict__ h) {
    int n = blockIdx.x;
    int d = threadIdx.x;
    if (d >= HIDDEN) return;
    const int offs[9] = {0, 119, 124, 136, 148, 158, 164, 170, 172};
    float acc = 0.0f;
#pragma unroll
    for (int f = 0; f < 9; ++f) {
        int idx = x[n * 9 + f] + offs[f];
        acc += emb[idx * HIDDEN + d];
    }
    h[n * HIDDEN + d] = acc;
}

// ---- tiled matmul: 64-node tile, W + h-tile in LDS, 4x4 register tile ----
#define MM_NODES 64
#define WL_PAD   10032
__global__ __launch_bounds__(512) void matmul_kernel(const float* __restrict__ h,
                                                     const float* __restrict__ W,
                                                     float* __restrict__ out) {
    __shared__ float Wl[WL_PAD];
    __shared__ float hl[MM_NODES * HIDDEN];
    int tid = threadIdx.x;
    int nb = blockIdx.x * MM_NODES;

    for (int i = tid; i < WL_PAD; i += 512)
        Wl[i] = (i < HIDDEN * HIDDEN) ? W[i] : 0.0f;
    for (int i = tid; i < MM_NODES * HIDDEN; i += 512) {
        int n = i / HIDDEN;
        hl[i] = (nb + n < N_NODES) ? h[(size_t)(nb + n) * HIDDEN + (i % HIDDEN)] : 0.0f;
    }
    __syncthreads();

    int tx = tid & 31;
    int ty = tid >> 5;  // 0..15

    float4 acc[4];
#pragma unroll
    for (int jn = 0; jn < 4; ++jn) acc[jn] = make_float4(0.f, 0.f, 0.f, 0.f);

    for (int kk = 0; kk < HIDDEN; kk += 4) {
        float hs[4][4];
#pragma unroll
        for (int jn = 0; jn < 4; ++jn) {
            float4 hv = *(const float4*)&hl[(ty + 16 * jn) * HIDDEN + kk];
            hs[jn][0] = hv.x; hs[jn][1] = hv.y; hs[jn][2] = hv.z; hs[jn][3] = hv.w;
        }
#pragma unroll
        for (int dk = 0; dk < 4; ++dk) {
            float4 wv = *(const float4*)&Wl[(kk + dk) * HIDDEN + 4 * tx];
#pragma unroll
            for (int jn = 0; jn < 4; ++jn) {
                acc[jn].x += hs[jn][dk] * wv.x;
                acc[jn].y += hs[jn][dk] * wv.y;
                acc[jn].z += hs[jn][dk] * wv.z;
                acc[jn].w += hs[jn][dk] * wv.w;
            }
        }
    }

    if (tx < 25) {
#pragma unroll
        for (int jn = 0; jn < 4; ++jn) {
            int n = nb + ty + 16 * jn;
            if (n < N_NODES)
                *(float4*)&out[(size_t)n * HIDDEN + 4 * tx] = acc[jn];
        }
    }
}

// ---- GCN aggregation: wave per node, float2 lanes, unroll-4, monotone early-exit ----
// All messages invclip(w*v) are > 0, so acc is monotone nondecreasing. The final
// invclip(acc/cnt) saturates to exactly 0.01 once acc >= 100*cnt; when every lane
// has crossed that bound the remaining edges provably cannot change the output.
__global__ __launch_bounds__(256) void agg_kernel(
        const float* __restrict__ hw, const int* __restrict__ csr_off,
        const int2* __restrict__ csr_pack, const float* __restrict__ dinv,
        const int* __restrict__ deg, const float* __restrict__ bias,
        float* __restrict__ out, int relu) {
    int wid  = (blockIdx.x * blockDim.x + threadIdx.x) >> 6;
    int lane = threadIdx.x & 63;
    if (wid >= N_NODES) return;
    int n = wid;
    bool act = lane < 50;  // lane owns dims 2*lane, 2*lane+1
    const float2* hw2 = (const float2*)hw;

    float cnt = (float)deg[n];
    float thr = 100.0f * cnt;

    float dn  = dinv[n];
    float nrm = dn * dn;  // self-loop norm
    float2 acc;
    if (act) {
        float2 v = hw2[(size_t)n * 50 + lane];
        acc.x = invclip(nrm * v.x);
        acc.y = invclip(nrm * v.y);
    } else {
        acc.x = 3.0e38f;  // inactive lanes never block the __all check
        acc.y = 3.0e38f;
    }

    int beg = csr_off[n], end = csr_off[n + 1];
    int i = beg;
    for (; i + 4 <= end; i += 4) {
        int2 p0 = csr_pack[i];
        int2 p1 = csr_pack[i + 1];
        int2 p2 = csr_pack[i + 2];
        int2 p3 = csr_pack[i + 3];
        float2 v0 = act ? hw2[(size_t)p0.x * 50 + lane] : make_float2(1.f, 1.f);
        float2 v1 = act ? hw2[(size_t)p1.x * 50 + lane] : make_float2(1.f, 1.f);
        float2 v2 = act ? hw2[(size_t)p2.x * 50 + lane] : make_float2(1.f, 1.f);
        float2 v3 = act ? hw2[(size_t)p3.x * 50 + lane] : make_float2(1.f, 1.f);
        float w0 = __int_as_float(p0.y), w1 = __int_as_float(p1.y);
        float w2 = __int_as_float(p2.y), w3 = __int_as_float(p3.y);
        acc.x += invclip(w0 * v0.x); acc.y += invclip(w0 * v0.y);
        acc.x += invclip(w1 * v1.x); acc.y += invclip(w1 * v1.y);
        acc.x += invclip(w2 * v2.x); acc.y += invclip(w2 * v2.y);
        acc.x += invclip(w3 * v3.x); acc.y += invclip(w3 * v3.y);
        if (__all((acc.x >= thr) & (acc.y >= thr))) { i = end; break; }
    }
    for (; i < end; ++i) {
        int2 p = csr_pack[i];
        float2 v = act ? hw2[(size_t)p.x * 50 + lane] : make_float2(1.f, 1.f);
        float w = __int_as_float(p.y);
        acc.x += invclip(w * v.x);
        acc.y += invclip(w * v.y);
    }

    if (act) {
        float rcnt = rcp_fast(cnt);
        float2 o;
        o.x = invclip(acc.x * rcnt) + bias[2 * lane];
        o.y = invclip(acc.y * rcnt) + bias[2 * lane + 1];
        if (relu) { o.x = fmaxf(o.x, 0.f); o.y = fmaxf(o.y, 0.f); }
        *(float2*)&out[(size_t)n * HIDDEN + 2 * lane] = o;
    }
}

// ---- fused mean-pool + linear head (batch sorted -> binary search range) ----
__global__ void pool_final_kernel(const float* __restrict__ h, const int* __restrict__ batch,
                                  const float* __restrict__ Wlin, const float* __restrict__ blin,
                                  float* __restrict__ out) {
    int g = blockIdx.x;
    int t = threadIdx.x;  // 128 = NUM_TASKS
    __shared__ float pl[HIDDEN];

    int lo = 0, hi = N_NODES;
    while (lo < hi) { int mid = (lo + hi) >> 1; if (batch[mid] < g) lo = mid + 1; else hi = mid; }
    int start = lo;
    hi = N_NODES;
    while (lo < hi) { int mid = (lo + hi) >> 1; if (batch[mid] < g + 1) lo = mid + 1; else hi = mid; }
    int end = lo;

    float inv = 1.0f / fmaxf((float)(end - start), 1.0f);
    if (t < HIDDEN) {
        float acc = 0.f;
        for (int n = start; n < end; ++n) acc += h[(size_t)n * HIDDEN + t];
        pl[t] = acc * inv;
    }
    __syncthreads();

    float o = 0.f;
#pragma unroll 4
    for (int j = 0; j < HIDDEN; ++j) o += pl[j] * Wlin[j * NUM_TASKS + t];
    out[(size_t)g * NUM_TASKS + t] = o + blin[t];
}

extern "C" void kernel_launch(void* const* d_in, const int* in_sizes, int n_in,
                              void* d_out, int out_size, void* d_ws, size_t ws_size,
                              hipStream_t stream) {
    const int*   x     = (const int*)d_in[0];
    const int*   ei    = (const int*)d_in[1];
    const int*   batch = (const int*)d_in[2];
    const float* emb   = (const float*)d_in[3];
    const float* W1    = (const float*)d_in[4];
    const float* b1    = (const float*)d_in[5];
    const float* W2    = (const float*)d_in[6];
    const float* b2    = (const float*)d_in[7];
    const float* Wlin  = (const float*)d_in[8];
    const float* blin  = (const float*)d_in[9];
    float* out = (float*)d_out;

    const int* row = ei;             // edge_index[0] = source
    const int* col = ei + N_EDGES;   // edge_index[1] = target

    char* ws = (char*)d_ws;
    auto alloc = [&](size_t bytes) -> char* {
        char* p = ws;
        ws += (bytes + 255) & ~(size_t)255;
        return p;
    };
    int*   deg      = (int*)  alloc((size_t)N_NODES * 4);
    int*   cursor   = (int*)  alloc((size_t)N_NODES * 4);
    int*   csr_off  = (int*)  alloc((size_t)(N_NODES + 1) * 4);
    float* dinv     = (float*)alloc((size_t)N_NODES * 4);
    int2*  csr_pack = (int2*) alloc((size_t)N_EDGES * 8);
    float* bufA     = (float*)alloc((size_t)N_NODES * HIDDEN * 4);
    float* bufB     = (float*)alloc((size_t)N_NODES * HIDDEN * 4);
    int*   bsum     = (int*)  alloc(256 * 4);

    const int SCAN_BLOCKS = (N_NODES + 255) / 256;  // 196

    init_kernel<<<(N_NODES + 255) / 256, 256, 0, stream>>>(deg, cursor);
    deg_count_kernel<<<(N_EDGES + 255) / 256, 256, 0, stream>>>(col, deg);
    blk_sum_kernel<<<SCAN_BLOCKS, 256, 0, stream>>>(deg, bsum);
    bsum_scan_kernel<<<1, 256, 0, stream>>>(bsum, SCAN_BLOCKS);
    blk_scan_kernel<<<SCAN_BLOCKS, 256, 0, stream>>>(deg, bsum, csr_off);
    dinv_kernel<<<(N_NODES + 255) / 256, 256, 0, stream>>>(deg, dinv);
    scatter_kernel<<<(N_EDGES + 255) / 256, 256, 0, stream>>>(row, col, csr_off, cursor, dinv,
                                                              csr_pack);
    encoder_kernel<<<N_NODES, 128, 0, stream>>>(x, emb, bufA);

    const int MM_BLOCKS = (N_NODES + MM_NODES - 1) / MM_NODES;  // 782
    // conv1: hw = h0 @ W1 ; agg -> relu -> h1
    matmul_kernel<<<MM_BLOCKS, 512, 0, stream>>>(bufA, W1, bufB);
    agg_kernel<<<(N_NODES + 3) / 4, 256, 0, stream>>>(bufB, csr_off, csr_pack,
                                                      dinv, deg, b1, bufA, 1);
    // conv2
    matmul_kernel<<<MM_BLOCKS, 512, 0, stream>>>(bufA, W2, bufB);
    agg_kernel<<<(N_NODES + 3) / 4, 256, 0, stream>>>(bufB, csr_off, csr_pack,
                                                      dinv, deg, b2, bufA, 0);

    pool_final_kernel<<<NUM_GRAPHS, 128, 0, stream>>>(bufA, batch, Wlin, blin, out);
}